// Round 2
// baseline (717.040 us; speedup 1.0000x reference)
//
#include <hip/hip_runtime.h>

// Problem constants (reference.py)
#define N_ENV 100000
#define DIM   400
#define MPTS  2000
#define NSTR  2000
#define NTRN  100

// GEMM tiling
#define BM 64                    // 64-row bands: LDS 54.3 KB -> 2 blocks/CU, 4 waves/SIMD
#define BK 32
#define NPAD 100096              // 1564 * 64
#define KPAD 416                 // 13 * 32
#define MPAD 2048                // 16 * 128
#define KTILES (KPAD / BK)       // 13
#define MSTEPS 8                 // 8 outer column steps (256 cols: 8 wcol waves x 32)
#define NBLK (NPAD / BM)         // 1564
#define LDST 424                 // LDS row stride in shorts: 848 B = 20 banks mod 32 -> 2-way (free)

typedef __attribute__((ext_vector_type(8))) short short8;
typedef __attribute__((ext_vector_type(4))) short short4v;
typedef __attribute__((ext_vector_type(4))) float float4v;

__device__ __forceinline__ unsigned short f2bf(float f) {
  union { float f; unsigned int u; } v; v.f = f;
  unsigned int u = v.u;
  u += 0x7fffu + ((u >> 16) & 1u);   // round-to-nearest-even
  return (unsigned short)(u >> 16);
}
__device__ __forceinline__ float bf2f(unsigned short s) {
  union { unsigned int u; float f; } v; v.u = ((unsigned int)s) << 16;
  return v.f;
}

// ---------------------------------------------------------------------------
// prep: wm[m] = weights[col_seg[m]] (0 in pad region), zero d_out
// ---------------------------------------------------------------------------
__global__ __launch_bounds__(256) void prep_kernel(
    const float* __restrict__ w, const int* __restrict__ col_seg,
    float* __restrict__ wm, float* __restrict__ out) {
  int t = blockIdx.x * 256 + threadIdx.x;
  if (t < MPAD) wm[t] = (t < MPTS) ? w[col_seg[t]] : 0.f;
  if (t < NSTR) out[t] = 0.f;
}

// ---------------------------------------------------------------------------
// B swizzle: fp32 support_points [MPTS,DIM] -> bf16 fragments in exact
// per-lane load order: Bsw[((pn*13+kt)*8+cf)*64+lane][e] =
//   B[pn*128+cf*16+(lane&15)][kt*32+(lane>>4)*8+e]  (0 outside MPTS/DIM)
// Inner-loop bf load becomes a fully coalesced global_load_dwordx4.
// (pn = 128-col panel index, 0..15 — layout unchanged across rounds)
// ---------------------------------------------------------------------------
__global__ __launch_bounds__(256) void bswz_kernel(
    const float* __restrict__ sp, short8* __restrict__ Bsw) {
  int u = blockIdx.x * 256 + threadIdx.x;     // < 16*13*8*64 = 106496
  int lane = u & 63;
  int v = u >> 6;          // ((pn*13+kt)*8+cf)
  int cf = v & 7;
  int w = v >> 3;          // pn*13+kt
  int kt = w % 13;
  int pn = w / 13;
  int col = pn * 128 + cf * 16 + (lane & 15);
  int kb  = kt * 32 + ((lane >> 4) << 3);
  short8 o = (short8){0, 0, 0, 0, 0, 0, 0, 0};
  if (col < MPTS && kb < DIM) {   // DIM divisible by 8: chunks never straddle
    const float* p = sp + (size_t)col * DIM + kb;
    float4 a = *(const float4*)p;
    float4 b = *(const float4*)(p + 4);
    o[0] = (short)f2bf(a.x); o[1] = (short)f2bf(a.y);
    o[2] = (short)f2bf(a.z); o[3] = (short)f2bf(a.w);
    o[4] = (short)f2bf(b.x); o[5] = (short)f2bf(b.y);
    o[6] = (short)f2bf(b.z); o[7] = (short)f2bf(b.w);
  }
  Bsw[u] = o;
}

// ---------------------------------------------------------------------------
// Fused GEMM. Round-2 change: BM 128->64. LDS drops to 54.3 KB -> 2 blocks
// co-resident per CU -> 16 waves/CU = 4 waves/SIMD (was 2), and 1564 finer
// blocks halve the end-of-grid quantization loss (782 blocks @ 1/CU measured
// as exactly 4 serial block-rounds = 433 us; MfmaUtil 16.6% == the 71.6 us
// MFMA floor / 433 -> pure latency exposure). One block's prologue now hides
// under the co-resident block's main loop.
// 8 waves = 1 wrow x 8 wcol, per-wave acc[4][2] (32 acc + 48 frag regs keeps
// total <=128 so 4 waves/SIMD actually fit; enforced by launch_bounds(512,4)).
// Per-wave B traffic ratio (wrow/BM = 1/64) unchanged -> same 2.66 GB L2 load.
// ---------------------------------------------------------------------------
__global__ __launch_bounds__(512, 4) void gemm_fused_kernel(
    const float* __restrict__ A,        // raw power_spectrum fp32 [N_ENV][DIM]
    const short8* __restrict__ Bsw,     // swizzled B fragments
    const float* __restrict__ wm,       // [MPAD]
    const int* __restrict__ row_seg,    // [N_ENV]
    float* __restrict__ out) {          // [NSTR]
  extern __shared__ unsigned short As[];   // [64][LDST] = 54272 B

  const int tid  = threadIdx.x;
  const int lane = tid & 63;
  const int wid  = tid >> 6;            // 0..7 = wcol
  const long row_base = (long)blockIdx.x * BM;

  // ---- Pass 1: coalesced fp32 -> bf16 -> LDS (unnormalized) --------------
  {
    const float4* Ag = (const float4*)(A + row_base * DIM);
    int rows_valid = (int)(N_ENV - row_base);          // may exceed 64
    if (rows_valid > BM) rows_valid = BM;
    for (int c = tid; c < BM * (DIM / 4); c += 512) {  // 6400 float4 chunks
      int row = c / 100;                               // 100 float4 per row
      int kc  = c - row * 100;
      uint2 packed = (uint2){0u, 0u};
      if (row < rows_valid) {
        float4 v = Ag[c];
        packed.x = (unsigned int)f2bf(v.x) | ((unsigned int)f2bf(v.y) << 16);
        packed.y = (unsigned int)f2bf(v.z) | ((unsigned int)f2bf(v.w) << 16);
      }
      *(uint2*)&As[row * LDST + kc * 4] = packed;
    }
    // Zero the K-pad tail [400, 424) for every row: the K-loop reads
    // fragments up to column 416 (kt=12, koff 16/24). 24 shorts = 3 x 16B.
    if (tid < BM) {
      uint4 z = (uint4){0u, 0u, 0u, 0u};
      uint4* zp = (uint4*)&As[tid * LDST + 400];
      zp[0] = z; zp[1] = z; zp[2] = z;
    }
  }
  __syncthreads();

  // ---- Pass 2+3: per-row norm from LDS, scale in place -------------------
  // 512 threads / 64 rows -> 8 threads per row, 52 shorts each (13 short4;
  // the q=7 slice covers [364,416): includes the zeroed pad, harmless).
  {
    int row = tid >> 3, q = tid & 7;
    unsigned short* rp = &As[row * LDST + q * 52];
    short4v vals[13];
    float ss = 0.f;
#pragma unroll
    for (int i = 0; i < 13; ++i) {
      vals[i] = *(const short4v*)(rp + i * 4);
#pragma unroll
      for (int e = 0; e < 4; ++e) {
        float f = bf2f((unsigned short)vals[i][e]);
        ss += f * f;
      }
    }
    ss += __shfl_xor(ss, 1);
    ss += __shfl_xor(ss, 2);
    ss += __shfl_xor(ss, 4);
    float rn = (ss > 0.f) ? rsqrtf(ss) : 0.f;
#pragma unroll
    for (int i = 0; i < 13; ++i) {
      short4v o;
#pragma unroll
      for (int e = 0; e < 4; ++e)
        o[e] = (short)f2bf(bf2f((unsigned short)vals[i][e]) * rn);
      *(short4v*)(rp + i * 4) = o;
    }
  }
  __syncthreads();

  // ---- Main loop ---------------------------------------------------------
  const int frow = lane & 15;
  const int koff = (lane >> 4) * 8;
  const unsigned short* Abase = &As[frow * LDST + koff];
  const int cfb  = (wid & 3) * 2;       // col-frag base (2 frags per wave)
  const int psel = wid >> 2;            // which of the 2 panels this step

  float vacc[4][4];
#pragma unroll
  for (int i = 0; i < 4; ++i)
#pragma unroll
    for (int r = 0; r < 4; ++r) vacc[i][r] = 0.f;

#pragma unroll 1
  for (int mt = 0; mt < MSTEPS; ++mt) {
    const int panel = mt * 2 + psel;    // 128-col panel in Bsw layout

    float4v acc[4][2];
#pragma unroll
    for (int i = 0; i < 4; ++i)
#pragma unroll
      for (int j = 0; j < 2; ++j) acc[i][j] = (float4v){0.f, 0.f, 0.f, 0.f};

    short8 afc[4], bfc[2], afn[4], bfn[2];
    const short8* Bp0 = Bsw + (((size_t)panel * KTILES) * 8 + cfb) * 64 + lane;
#pragma unroll
    for (int i = 0; i < 4; ++i)
      afc[i] = *(const short8*)(Abase + i * (16 * LDST));
#pragma unroll
    for (int j = 0; j < 2; ++j) bfc[j] = Bp0[j * 64];

#pragma unroll 1
    for (int kt = 0; kt < KTILES; ++kt) {
      if (kt < KTILES - 1) {
        const unsigned short* An = Abase + (kt + 1) * 32;
#pragma unroll
        for (int i = 0; i < 4; ++i)
          afn[i] = *(const short8*)(An + i * (16 * LDST));
        const short8* Bn =
            Bsw + (((size_t)panel * KTILES + kt + 1) * 8 + cfb) * 64 + lane;
#pragma unroll
        for (int j = 0; j < 2; ++j) bfn[j] = Bn[j * 64];
      }
#pragma unroll
      for (int i = 0; i < 4; ++i)
#pragma unroll
        for (int j = 0; j < 2; ++j)
          acc[i][j] = __builtin_amdgcn_mfma_f32_16x16x32_bf16(
              afc[i], bfc[j], acc[i][j], 0, 0, 0);
      if (kt < KTILES - 1) {
#pragma unroll
        for (int i = 0; i < 4; ++i) afc[i] = afn[i];
#pragma unroll
        for (int j = 0; j < 2; ++j) bfc[j] = bfn[j];
      }
    }

    // epilogue: vacc[row] += wm[col] * C^2 over this wave's 2 col-frags
    float wmv[2];
#pragma unroll
    for (int j = 0; j < 2; ++j)
      wmv[j] = wm[panel * 128 + (cfb + j) * 16 + frow];
#pragma unroll
    for (int i = 0; i < 4; ++i)
#pragma unroll
      for (int r = 0; r < 4; ++r) {
        float s = 0.f;
#pragma unroll
        for (int j = 0; j < 2; ++j) {
          float c = acc[i][j][r];
          s += wmv[j] * c * c;
        }
        vacc[i][r] += s;
      }
  }

  // cross-lane reduce over 16-lane groups (same C/D rows), then atomics
#pragma unroll
  for (int i = 0; i < 4; ++i)
#pragma unroll
    for (int r = 0; r < 4; ++r) {
      float s = vacc[i][r];
      s += __shfl_xor(s, 1);
      s += __shfl_xor(s, 2);
      s += __shfl_xor(s, 4);
      s += __shfl_xor(s, 8);
      if ((lane & 15) == 0) {
        long n = row_base + i * 16 + (lane >> 4) * 4 + r;
        if (n < N_ENV) atomicAdd(&out[row_seg[n]], s);
      }
    }
}

// ---------------------------------------------------------------------------
extern "C" void kernel_launch(void* const* d_in, const int* in_sizes, int n_in,
                              void* d_out, int out_size, void* d_ws, size_t ws_size,
                              hipStream_t stream) {
  const float* ps      = (const float*)d_in[0];  // [N_ENV, DIM]
  const float* sp      = (const float*)d_in[1];  // [MPTS, DIM]
  const float* w       = (const float*)d_in[2];  // [1, NTRN]
  // d_in[3] = all_species: unused by the reference
  const int*   row_seg = (const int*)d_in[4];    // [N_ENV]
  const int*   col_seg = (const int*)d_in[5];    // [MPTS]
  float* out = (float*)d_out;                    // [NSTR]

  char* ws = (char*)d_ws;
  const size_t B_BYTES = (size_t)16 * KTILES * 8 * 64 * 16;  // 1,703,936
  short8* Bsw = (short8*)ws;
  float*  wm  = (float*)(ws + B_BYTES);

  const int LDS_BYTES = BM * LDST * 2;   // 54272
  (void)hipFuncSetAttribute((const void*)gemm_fused_kernel,
                            hipFuncAttributeMaxDynamicSharedMemorySize,
                            LDS_BYTES);

  prep_kernel<<<MPAD / 256, 256, 0, stream>>>(w, col_seg, wm, out);
  bswz_kernel<<<(16 * KTILES * 8 * 64) / 256, 256, 0, stream>>>(sp, Bsw);
  gemm_fused_kernel<<<NBLK, 512, LDS_BYTES, stream>>>(ps, Bsw, wm, row_seg, out);
}

// Round 4
// 591.969 us; speedup vs baseline: 1.2113x; 1.2113x over previous
//
#include <hip/hip_runtime.h>

// Problem constants (reference.py)
#define N_ENV 100000
#define DIM   400
#define MPTS  2000
#define NSTR  2000
#define NTRN  100

// GEMM tiling
#define BM 512                   // rows per block: 8 waves x 64 rows, A in registers
#define BK 32
#define NPAD 100352              // 196 * 512
#define KPAD 416                 // 13 * 32
#define MPAD 2048                // 16 * 128
#define KTILES (KPAD / BK)       // 13
#define NBLK (NPAD / BM)         // 196
#define CSTEPS 32                // 32 column steps x 64 cols = 2048
#define CHUNK 64                 // prologue normalize chunk (rows)
#define LDST 424                 // LDS row stride in shorts: 848 B

typedef __attribute__((ext_vector_type(8))) short short8;
typedef __attribute__((ext_vector_type(4))) short short4v;
typedef __attribute__((ext_vector_type(4))) float float4v;

__device__ __forceinline__ unsigned short f2bf(float f) {
  union { float f; unsigned int u; } v; v.f = f;
  unsigned int u = v.u;
  u += 0x7fffu + ((u >> 16) & 1u);   // round-to-nearest-even
  return (unsigned short)(u >> 16);
}
__device__ __forceinline__ float bf2f(unsigned short s) {
  union { unsigned int u; float f; } v; v.u = ((unsigned int)s) << 16;
  return v.f;
}

// ---------------------------------------------------------------------------
// prep: wm[m] = weights[col_seg[m]] (0 in pad region), zero d_out
// ---------------------------------------------------------------------------
__global__ __launch_bounds__(256) void prep_kernel(
    const float* __restrict__ w, const int* __restrict__ col_seg,
    float* __restrict__ wm, float* __restrict__ out) {
  int t = blockIdx.x * 256 + threadIdx.x;
  if (t < MPAD) wm[t] = (t < MPTS) ? w[col_seg[t]] : 0.f;
  if (t < NSTR) out[t] = 0.f;
}

// ---------------------------------------------------------------------------
// B swizzle: fp32 support_points [MPTS,DIM] -> bf16 fragments in exact
// per-lane load order: Bsw[((pn*13+kt)*8+cf)*64+lane][e] =
//   B[pn*128+cf*16+(lane&15)][kt*32+(lane>>4)*8+e]  (0 outside MPTS/DIM)
// Main-loop bf load is a wave-uniform-address global_load_dwordx4 -> all 8
// waves of a block read the SAME stream (L1 dedup).
// ---------------------------------------------------------------------------
__global__ __launch_bounds__(256) void bswz_kernel(
    const float* __restrict__ sp, short8* __restrict__ Bsw) {
  int u = blockIdx.x * 256 + threadIdx.x;     // < 16*13*8*64 = 106496
  int lane = u & 63;
  int v = u >> 6;          // ((pn*13+kt)*8+cf)
  int cf = v & 7;
  int w = v >> 3;          // pn*13+kt
  int kt = w % 13;
  int pn = w / 13;
  int col = pn * 128 + cf * 16 + (lane & 15);
  int kb  = kt * 32 + ((lane >> 4) << 3);
  short8 o = (short8){0, 0, 0, 0, 0, 0, 0, 0};
  if (col < MPTS && kb < DIM) {   // DIM divisible by 8: chunks never straddle
    const float* p = sp + (size_t)col * DIM + kb;
    float4 a = *(const float4*)p;
    float4 b = *(const float4*)(p + 4);
    o[0] = (short)f2bf(a.x); o[1] = (short)f2bf(a.y);
    o[2] = (short)f2bf(a.z); o[3] = (short)f2bf(a.w);
    o[4] = (short)f2bf(b.x); o[5] = (short)f2bf(b.y);
    o[6] = (short)f2bf(b.z); o[7] = (short)f2bf(b.w);
  }
  Bsw[u] = o;
}

// ---------------------------------------------------------------------------
// Round-4 = round-3 structure with the nontemporal-load type fixed
// (__builtin_nontemporal_load requires a clang ext-vector pointer, not
// HIP_vector_type float4).
// Theory recap: B re-reads via L3 were the bottleneck (round-2: 2x waves,
// slower). So:
//  * Each wave owns 64 rows; its 52 A-fragments (4 row-frags x 13 kt) are
//    loaded ONCE into registers via a chunked LDS-normalize prologue.
//    Main loop has ZERO A traffic (no LDS, no global).
//  * All 8 waves sweep the SAME wave-uniform B fragment stream: B per block
//    = 1.7 MB fresh, x196 blocks = 333 MB total (was ~2.7 GB through L3).
//  * A fp32 staging uses nontemporal loads so the 160 MB A stream doesn't
//    evict B from the XCD L2s.
//  * acc[4][4] per 64-col step, 32 steps x 13 kt (kt fully unrolled so all
//    af[i][kt] indexing is static -> stays in VGPRs).
// ---------------------------------------------------------------------------
__global__ __launch_bounds__(512, 2) void gemm_fused_kernel(
    const float* __restrict__ A,        // raw power_spectrum fp32 [N_ENV][DIM]
    const short8* __restrict__ Bsw,     // swizzled B fragments
    const float* __restrict__ wm,       // [MPAD]
    const int* __restrict__ row_seg,    // [N_ENV]
    float* __restrict__ out) {          // [NSTR]
  __shared__ unsigned short As[CHUNK * LDST];   // 54272 B (static)

  const int tid  = threadIdx.x;
  const int lane = tid & 63;
  const int wid  = tid >> 6;            // 0..7: which 64-row group this wave owns
  const int frow = lane & 15;
  const int koff = (lane >> 4) * 8;
  const long row_base = (long)blockIdx.x * BM;

  short8 af[4][13];                     // 104 VGPRs: this wave's A, resident

  // ---- Prologue: 8 chunks of 64 rows: stage -> normalize -> extract ------
  for (int ch = 0; ch < 8; ++ch) {
    const long rb = row_base + (long)ch * CHUNK;
    int rows_valid = (int)(N_ENV - rb);
    if (rows_valid > CHUNK) rows_valid = CHUNK;
    if (rows_valid < 0) rows_valid = 0;

    // stage: coalesced fp32 -> bf16 -> LDS (nontemporal: don't thrash L2)
    {
      const float4v* Ag = (const float4v*)(A + rb * DIM);
      for (int c = tid; c < CHUNK * (DIM / 4); c += 512) {  // 6400 chunks
        int row = c / 100;                                  // 100 float4/row
        int kc  = c - row * 100;
        uint2 packed = (uint2){0u, 0u};
        if (row < rows_valid) {
          float4v v = __builtin_nontemporal_load(&Ag[c]);
          packed.x = (unsigned int)f2bf(v[0]) | ((unsigned int)f2bf(v[1]) << 16);
          packed.y = (unsigned int)f2bf(v[2]) | ((unsigned int)f2bf(v[3]) << 16);
        }
        *(uint2*)&As[row * LDST + kc * 4] = packed;
      }
      if (tid < CHUNK) {   // zero K-pad [400,424): read by kt=12 fragments
        uint4 z = (uint4){0u, 0u, 0u, 0u};
        uint4* zp = (uint4*)&As[tid * LDST + 400];
        zp[0] = z; zp[1] = z; zp[2] = z;
      }
    }
    __syncthreads();

    // normalize in place: 8 threads per row, 52 shorts each
    {
      int row = tid >> 3, q = tid & 7;
      unsigned short* rp = &As[row * LDST + q * 52];
      short4v vals[13];
      float ss = 0.f;
#pragma unroll
      for (int i = 0; i < 13; ++i) {
        vals[i] = *(const short4v*)(rp + i * 4);
#pragma unroll
        for (int e = 0; e < 4; ++e) {
          float f = bf2f((unsigned short)vals[i][e]);
          ss += f * f;
        }
      }
      ss += __shfl_xor(ss, 1);
      ss += __shfl_xor(ss, 2);
      ss += __shfl_xor(ss, 4);
      float rn = (ss > 0.f) ? rsqrtf(ss) : 0.f;
#pragma unroll
      for (int i = 0; i < 13; ++i) {
        short4v o;
#pragma unroll
        for (int e = 0; e < 4; ++e)
          o[e] = (short)f2bf(bf2f((unsigned short)vals[i][e]) * rn);
        *(short4v*)(rp + i * 4) = o;
      }
    }
    __syncthreads();

    // extract: owning wave pulls its 52 fragments into registers
    if (wid == ch) {
      const unsigned short* Ab = &As[frow * LDST + koff];
#pragma unroll
      for (int i = 0; i < 4; ++i)
#pragma unroll
        for (int kt = 0; kt < 13; ++kt)
          af[i][kt] = *(const short8*)(Ab + i * (16 * LDST) + kt * 32);
    }
    __syncthreads();   // before next chunk overwrites LDS
  }

  // ---- Main loop: pure MFMA + wave-uniform B stream ----------------------
  float vacc[4][4];
#pragma unroll
  for (int i = 0; i < 4; ++i)
#pragma unroll
    for (int r = 0; r < 4; ++r) vacc[i][r] = 0.f;

  short8 bfc[4], bfn[4];
  // prefetch s=0, kt=0  (frag index ((pn*13+kt)*8+cf)*64+lane)
#pragma unroll
  for (int j = 0; j < 4; ++j) bfc[j] = Bsw[(size_t)j * 64 + lane];

#pragma unroll 1
  for (int s = 0; s < CSTEPS; ++s) {
    float4v acc[4][4];
#pragma unroll
    for (int i = 0; i < 4; ++i)
#pragma unroll
      for (int j = 0; j < 4; ++j) acc[i][j] = (float4v){0.f, 0.f, 0.f, 0.f};

#pragma unroll
    for (int kt = 0; kt < KTILES; ++kt) {
      // prefetch next kt (or next step's kt=0); static per unrolled iter
      {
        int ns  = (kt == KTILES - 1) ? s + 1 : s;
        int nkt = (kt == KTILES - 1) ? 0 : kt + 1;
        if (ns < CSTEPS) {
          const int npn = ns >> 1, ncfb = (ns & 1) * 4;
          const size_t base = (((size_t)npn * KTILES + nkt) * 8 + ncfb) * 64 + lane;
#pragma unroll
          for (int j = 0; j < 4; ++j) bfn[j] = Bsw[base + (size_t)j * 64];
        }
      }
#pragma unroll
      for (int i = 0; i < 4; ++i)
#pragma unroll
        for (int j = 0; j < 4; ++j)
          acc[i][j] = __builtin_amdgcn_mfma_f32_16x16x32_bf16(
              af[i][kt], bfc[j], acc[i][j], 0, 0, 0);
#pragma unroll
      for (int j = 0; j < 4; ++j) bfc[j] = bfn[j];
    }

    // epilogue: vacc[row] += wm[col] * C^2 over this step's 4 col-frags
    float wmv[4];
#pragma unroll
    for (int j = 0; j < 4; ++j)
      wmv[j] = wm[s * 64 + j * 16 + frow];
#pragma unroll
    for (int i = 0; i < 4; ++i)
#pragma unroll
      for (int r = 0; r < 4; ++r) {
        float sum = 0.f;
#pragma unroll
        for (int j = 0; j < 4; ++j) {
          float c = acc[i][j][r];
          sum += wmv[j] * c * c;
        }
        vacc[i][r] += sum;
      }
  }

  // cross-lane reduce over 16-lane groups (same C/D rows), then atomics
#pragma unroll
  for (int i = 0; i < 4; ++i)
#pragma unroll
    for (int r = 0; r < 4; ++r) {
      float s = vacc[i][r];
      s += __shfl_xor(s, 1);
      s += __shfl_xor(s, 2);
      s += __shfl_xor(s, 4);
      s += __shfl_xor(s, 8);
      if ((lane & 15) == 0) {
        long n = row_base + wid * 64 + i * 16 + (lane >> 4) * 4 + r;
        if (n < N_ENV) atomicAdd(&out[row_seg[n]], s);
      }
    }
}

// ---------------------------------------------------------------------------
extern "C" void kernel_launch(void* const* d_in, const int* in_sizes, int n_in,
                              void* d_out, int out_size, void* d_ws, size_t ws_size,
                              hipStream_t stream) {
  const float* ps      = (const float*)d_in[0];  // [N_ENV, DIM]
  const float* sp      = (const float*)d_in[1];  // [MPTS, DIM]
  const float* w       = (const float*)d_in[2];  // [1, NTRN]
  // d_in[3] = all_species: unused by the reference
  const int*   row_seg = (const int*)d_in[4];    // [N_ENV]
  const int*   col_seg = (const int*)d_in[5];    // [MPTS]
  float* out = (float*)d_out;                    // [NSTR]

  char* ws = (char*)d_ws;
  const size_t B_BYTES = (size_t)16 * KTILES * 8 * 64 * 16;  // 1,703,936
  short8* Bsw = (short8*)ws;
  float*  wm  = (float*)(ws + B_BYTES);

  prep_kernel<<<MPAD / 256, 256, 0, stream>>>(w, col_seg, wm, out);
  bswz_kernel<<<(16 * KTILES * 8 * 64) / 256, 256, 0, stream>>>(sp, Bsw);
  gemm_fused_kernel<<<NBLK, 512, 0, stream>>>(ps, Bsw, wm, row_seg, out);
}

// Round 6
// 440.968 us; speedup vs baseline: 1.6261x; 1.3424x over previous
//
#include <hip/hip_runtime.h>

// Problem constants (reference.py)
#define N_ENV 100000
#define DIM   400
#define MPTS  2000
#define NSTR  2000
#define NTRN  100

// GEMM tiling
#define BM 256                   // rows per block: 8 waves x 32 rows, A in registers
#define NPAD 100352              // 392 * 256
#define KPAD 416                 // 13 * 32
#define MPAD 2048                // 16 * 128
#define KTILES 13
#define NBLK (NPAD / BM)         // 392
#define CSTEPS 32                // 32 column steps x 64 cols = 2048
#define CHUNK 64                 // prologue normalize chunk (rows)
#define LDST 424                 // prologue LDS row stride in shorts
#define RINGB 53248              // bytes per cstep B buffer: 52 frags * 1024

typedef __attribute__((ext_vector_type(8))) short short8;
typedef __attribute__((ext_vector_type(4))) short short4v;
typedef __attribute__((ext_vector_type(4))) float float4v;

#define AS1(p) ((const __attribute__((address_space(1))) void*)(p))
#define AS3(p) ((__attribute__((address_space(3))) void*)(p))

__device__ __forceinline__ unsigned short f2bf(float f) {
  union { float f; unsigned int u; } v; v.f = f;
  unsigned int u = v.u;
  u += 0x7fffu + ((u >> 16) & 1u);   // round-to-nearest-even
  return (unsigned short)(u >> 16);
}
__device__ __forceinline__ float bf2f(unsigned short s) {
  union { unsigned int u; float f; } v; v.u = ((unsigned int)s) << 16;
  return v.f;
}

// ---------------------------------------------------------------------------
// prep: wm[m] = weights[col_seg[m]] (0 in pad region), zero d_out
// ---------------------------------------------------------------------------
__global__ __launch_bounds__(256) void prep_kernel(
    const float* __restrict__ w, const int* __restrict__ col_seg,
    float* __restrict__ wm, float* __restrict__ out) {
  int t = blockIdx.x * 256 + threadIdx.x;
  if (t < MPAD) wm[t] = (t < MPTS) ? w[col_seg[t]] : 0.f;
  if (t < NSTR) out[t] = 0.f;
}

// ---------------------------------------------------------------------------
// B swizzle: fp32 support_points [MPTS,DIM] -> bf16 fragments:
// Bsw[((pn*13+kt)*8+cf)*64+lane][e] =
//   B[pn*128+cf*16+(lane&15)][kt*32+(lane>>4)*8+e]  (0 outside MPTS/DIM)
// One frag = 64 lanes x 16 B = 1 KB, contiguous -> global_load_lds-able.
// ---------------------------------------------------------------------------
__global__ __launch_bounds__(256) void bswz_kernel(
    const float* __restrict__ sp, short8* __restrict__ Bsw) {
  int u = blockIdx.x * 256 + threadIdx.x;     // < 16*13*8*64 = 106496
  int lane = u & 63;
  int v = u >> 6;          // ((pn*13+kt)*8+cf)
  int cf = v & 7;
  int w = v >> 3;          // pn*13+kt
  int kt = w % 13;
  int pn = w / 13;
  int col = pn * 128 + cf * 16 + (lane & 15);
  int kb  = kt * 32 + ((lane >> 4) << 3);
  short8 o = (short8){0, 0, 0, 0, 0, 0, 0, 0};
  if (col < MPTS && kb < DIM) {   // DIM divisible by 8: chunks never straddle
    const float* p = sp + (size_t)col * DIM + kb;
    float4 a = *(const float4*)p;
    float4 b = *(const float4*)(p + 4);
    o[0] = (short)f2bf(a.x); o[1] = (short)f2bf(a.y);
    o[2] = (short)f2bf(a.z); o[3] = (short)f2bf(a.w);
    o[4] = (short)f2bf(b.x); o[5] = (short)f2bf(b.y);
    o[6] = (short)f2bf(b.z); o[7] = (short)f2bf(b.w);
  }
  Bsw[u] = o;
}

// ---------------------------------------------------------------------------
// Round-6 = round-5 resubmitted verbatim (round-5 bench was an infra
// failure: "MI355X container failed twice"; kernel audit found no hang
// hazard — uniform barriers, correct global_load_lds dest semantics,
// double-buffer hazard covered by the per-cstep __syncthreads).
// Structure recap:
//  * 8 waves x 32 rows: af[2][13] = 104 VGPR + acc[2][4]=32 + vacc=8 -> ~180.
//    No launch_bounds min-waves (R2/R4 spill lesson).
//  * B staged per-cstep into a 2 x 52 KB LDS ring via global_load_lds:
//    stages for cstep s+1 issue at the top of cstep s, then 13 kt-steps of
//    MFMA (~8000 cyc) hide the global latency; one barrier per cstep.
//    Each B byte crosses L2 ONCE per block (was 8x, per-wave).
//  * Inner loop: bf from LDS (linear ds_read_b128, conflict-free), af from
//    registers. Zero per-kt-step global traffic.
// ---------------------------------------------------------------------------
__global__ __launch_bounds__(512, 1) void gemm_fused_kernel(
    const float* __restrict__ A,        // raw power_spectrum fp32 [N_ENV][DIM]
    const short8* __restrict__ Bsw,     // swizzled B fragments
    const float* __restrict__ wm,       // [MPAD]
    const int* __restrict__ row_seg,    // [N_ENV]
    float* __restrict__ out) {          // [NSTR]
  extern __shared__ unsigned char smem[];          // 2*RINGB = 106496 B
  unsigned short* As = (unsigned short*)smem;      // prologue staging view

  const int tid  = threadIdx.x;
  const int lane = tid & 63;
  const int wid  = tid >> 6;            // 0..7: owns rows [wid*32, wid*32+32)
  const int frow = lane & 15;
  const int koff = (lane >> 4) * 8;
  const long row_base = (long)blockIdx.x * BM;

  short8 af[2][13];                     // 104 VGPRs: this wave's A, resident

  // ---- Prologue: 4 chunks of 64 rows: stage -> normalize -> extract ------
  for (int ch = 0; ch < 4; ++ch) {
    const long rb = row_base + (long)ch * CHUNK;
    int rows_valid = (int)(N_ENV - rb);
    if (rows_valid > CHUNK) rows_valid = CHUNK;
    if (rows_valid < 0) rows_valid = 0;

    // stage: coalesced fp32 -> bf16 -> LDS (nontemporal: A has zero reuse)
    {
      const float4v* Ag = (const float4v*)(A + rb * DIM);
      for (int c = tid; c < CHUNK * (DIM / 4); c += 512) {  // 6400 chunks
        int row = c / 100;                                  // 100 float4/row
        int kc  = c - row * 100;
        uint2 packed = (uint2){0u, 0u};
        if (row < rows_valid) {
          float4v v = __builtin_nontemporal_load(&Ag[c]);
          packed.x = (unsigned int)f2bf(v[0]) | ((unsigned int)f2bf(v[1]) << 16);
          packed.y = (unsigned int)f2bf(v[2]) | ((unsigned int)f2bf(v[3]) << 16);
        }
        *(uint2*)&As[row * LDST + kc * 4] = packed;
      }
      if (tid < CHUNK) {   // zero K-pad [400,424): read by kt=12 fragments
        uint4 z = (uint4){0u, 0u, 0u, 0u};
        uint4* zp = (uint4*)&As[tid * LDST + 400];
        zp[0] = z; zp[1] = z; zp[2] = z;
      }
    }
    __syncthreads();

    // normalize in place: 8 threads per row, 52 shorts each
    {
      int row = tid >> 3, q = tid & 7;
      unsigned short* rp = &As[row * LDST + q * 52];
      short4v vals[13];
      float ss = 0.f;
#pragma unroll
      for (int i = 0; i < 13; ++i) {
        vals[i] = *(const short4v*)(rp + i * 4);
#pragma unroll
        for (int e = 0; e < 4; ++e) {
          float f = bf2f((unsigned short)vals[i][e]);
          ss += f * f;
        }
      }
      ss += __shfl_xor(ss, 1);
      ss += __shfl_xor(ss, 2);
      ss += __shfl_xor(ss, 4);
      float rn = (ss > 0.f) ? rsqrtf(ss) : 0.f;
#pragma unroll
      for (int i = 0; i < 13; ++i) {
        short4v o;
#pragma unroll
        for (int e = 0; e < 4; ++e)
          o[e] = (short)f2bf(bf2f((unsigned short)vals[i][e]) * rn);
        *(short4v*)(rp + i * 4) = o;
      }
    }
    __syncthreads();

    // extract: the two owning waves pull their 26 fragments into registers
    if ((wid >> 1) == ch) {
      const unsigned short* Ab = &As[((wid & 1) * 32 + frow) * LDST + koff];
#pragma unroll
      for (int i = 0; i < 2; ++i)
#pragma unroll
        for (int kt = 0; kt < 13; ++kt)
          af[i][kt] = *(const short8*)(Ab + i * (16 * LDST) + kt * 32);
    }
    __syncthreads();   // before next chunk (or ring) overwrites LDS
  }

  // ---- Main loop: LDS-ring B pipeline + register A -----------------------
  float vacc[2][4];
#pragma unroll
  for (int i = 0; i < 2; ++i)
#pragma unroll
    for (int r = 0; r < 4; ++r) vacc[i][r] = 0.f;

  // stage cstep s into ring buffer (s&1): 52 frags, spread over 8 waves
#define STAGE_CSTEP(s)                                                        \
  {                                                                           \
    const int pn_ = (s) >> 1, cfb_ = ((s) & 1) * 4;                           \
    unsigned char* buf_ = smem + (size_t)((s) & 1) * RINGB;                   \
    for (int f = wid; f < 52; f += 8) {                                       \
      int kt_ = f >> 2, j_ = f & 3;                                           \
      const short8* src_ =                                                    \
          Bsw + ((((size_t)pn_ * 13 + kt_) * 8) + cfb_ + j_) * 64 + lane;     \
      __builtin_amdgcn_global_load_lds(AS1(src_), AS3(buf_ + f * 1024),       \
                                       16, 0, 0);                             \
    }                                                                         \
  }

  STAGE_CSTEP(0);
  __syncthreads();   // compiler drains vmcnt before s_barrier -> buf0 ready

#pragma unroll 1
  for (int s = 0; s < CSTEPS; ++s) {
    if (s + 1 < CSTEPS) STAGE_CSTEP(s + 1);   // hidden under 13 kt of MFMA

    const unsigned short* buf =
        (const unsigned short*)(smem + (size_t)(s & 1) * RINGB);

    float4v acc[2][4];
#pragma unroll
    for (int i = 0; i < 2; ++i)
#pragma unroll
      for (int j = 0; j < 4; ++j) acc[i][j] = (float4v){0.f, 0.f, 0.f, 0.f};

#pragma unroll
    for (int kt = 0; kt < KTILES; ++kt) {
      short8 bf[4];
#pragma unroll
      for (int j = 0; j < 4; ++j)
        bf[j] = *(const short8*)(buf + (kt * 4 + j) * 512 + lane * 8);
#pragma unroll
      for (int i = 0; i < 2; ++i)
#pragma unroll
        for (int j = 0; j < 4; ++j)
          acc[i][j] = __builtin_amdgcn_mfma_f32_16x16x32_bf16(
              af[i][kt], bf[j], acc[i][j], 0, 0, 0);
    }

    // epilogue: vacc[row] += wm[col] * C^2 over this step's 4 col-frags
    float wmv[4];
#pragma unroll
    for (int j = 0; j < 4; ++j)
      wmv[j] = wm[s * 64 + j * 16 + frow];
#pragma unroll
    for (int i = 0; i < 2; ++i)
#pragma unroll
      for (int r = 0; r < 4; ++r) {
        float sum = 0.f;
#pragma unroll
        for (int j = 0; j < 4; ++j) {
          float c = acc[i][j][r];
          sum += wmv[j] * c * c;
        }
        vacc[i][r] += sum;
      }

    __syncthreads();   // all waves done reading buf[s&1]; stage(s+1) drained
  }

  // cross-lane reduce over 16-lane groups (same C/D rows), then atomics
#pragma unroll
  for (int i = 0; i < 2; ++i)
#pragma unroll
    for (int r = 0; r < 4; ++r) {
      float s = vacc[i][r];
      s += __shfl_xor(s, 1);
      s += __shfl_xor(s, 2);
      s += __shfl_xor(s, 4);
      s += __shfl_xor(s, 8);
      if ((lane & 15) == 0) {
        long n = row_base + wid * 32 + i * 16 + (lane >> 4) * 4 + r;
        if (n < N_ENV) atomicAdd(&out[row_seg[n]], s);
      }
    }
}

// ---------------------------------------------------------------------------
extern "C" void kernel_launch(void* const* d_in, const int* in_sizes, int n_in,
                              void* d_out, int out_size, void* d_ws, size_t ws_size,
                              hipStream_t stream) {
  const float* ps      = (const float*)d_in[0];  // [N_ENV, DIM]
  const float* sp      = (const float*)d_in[1];  // [MPTS, DIM]
  const float* w       = (const float*)d_in[2];  // [1, NTRN]
  // d_in[3] = all_species: unused by the reference
  const int*   row_seg = (const int*)d_in[4];    // [N_ENV]
  const int*   col_seg = (const int*)d_in[5];    // [MPTS]
  float* out = (float*)d_out;                    // [NSTR]

  char* ws = (char*)d_ws;
  const size_t B_BYTES = (size_t)16 * KTILES * 8 * 64 * 16;  // 1,703,936
  short8* Bsw = (short8*)ws;
  float*  wm  = (float*)(ws + B_BYTES);

  const int LDS_BYTES = 2 * RINGB;   // 106496
  (void)hipFuncSetAttribute((const void*)gemm_fused_kernel,
                            hipFuncAttributeMaxDynamicSharedMemorySize,
                            LDS_BYTES);

  prep_kernel<<<MPAD / 256, 256, 0, stream>>>(w, col_seg, wm, out);
  bswz_kernel<<<(16 * KTILES * 8 * 64) / 256, 256, 0, stream>>>(sp, Bsw);
  gemm_fused_kernel<<<NBLK, 512, LDS_BYTES, stream>>>(ps, Bsw, wm, row_seg, out);
}

// Round 7
// 438.057 us; speedup vs baseline: 1.6369x; 1.0066x over previous
//
#include <hip/hip_runtime.h>

// Problem constants (reference.py)
#define N_ENV 100000
#define DIM   400
#define MPTS  2000
#define NSTR  2000
#define NTRN  100

// GEMM tiling
#define BM 256                   // rows per block: 8 waves x 32 rows, A in registers
#define NPAD 100352              // 392 * 256
#define KPAD 416                 // 13 * 32
#define MPAD 2048                // 16 * 128
#define KTILES 13
#define NBLK (NPAD / BM)         // 392
#define CSTEPS 32                // 32 column steps x 64 cols = 2048
#define CHUNK 64                 // prologue normalize chunk (rows)
#define LDST 424                 // prologue LDS row stride in shorts
#define RINGB 53248              // bytes per cstep B buffer: 52 frags * 1024

typedef __attribute__((ext_vector_type(8))) short short8;
typedef __attribute__((ext_vector_type(4))) short short4v;
typedef __attribute__((ext_vector_type(4))) float float4v;

#define AS1(p) ((const __attribute__((address_space(1))) void*)(p))
#define AS3(p) ((__attribute__((address_space(3))) void*)(p))

__device__ __forceinline__ unsigned short f2bf(float f) {
  union { float f; unsigned int u; } v; v.f = f;
  unsigned int u = v.u;
  u += 0x7fffu + ((u >> 16) & 1u);   // round-to-nearest-even
  return (unsigned short)(u >> 16);
}
__device__ __forceinline__ float bf2f(unsigned short s) {
  union { unsigned int u; float f; } v; v.u = ((unsigned int)s) << 16;
  return v.f;
}

// ---------------------------------------------------------------------------
// prep: wm[m] = weights[col_seg[m]] (0 in pad region), zero d_out
// ---------------------------------------------------------------------------
__global__ __launch_bounds__(256) void prep_kernel(
    const float* __restrict__ w, const int* __restrict__ col_seg,
    float* __restrict__ wm, float* __restrict__ out) {
  int t = blockIdx.x * 256 + threadIdx.x;
  if (t < MPAD) wm[t] = (t < MPTS) ? w[col_seg[t]] : 0.f;
  if (t < NSTR) out[t] = 0.f;
}

// ---------------------------------------------------------------------------
// B swizzle: fp32 support_points [MPTS,DIM] -> bf16 fragments:
// Bsw[((pn*13+kt)*8+cf)*64+lane][e] =
//   B[pn*128+cf*16+(lane&15)][kt*32+(lane>>4)*8+e]  (0 outside MPTS/DIM)
// One frag = 64 lanes x 16 B = 1 KB, contiguous -> global_load_lds-able.
// ---------------------------------------------------------------------------
__global__ __launch_bounds__(256) void bswz_kernel(
    const float* __restrict__ sp, short8* __restrict__ Bsw) {
  int u = blockIdx.x * 256 + threadIdx.x;     // < 16*13*8*64 = 106496
  int lane = u & 63;
  int v = u >> 6;          // ((pn*13+kt)*8+cf)
  int cf = v & 7;
  int w = v >> 3;          // pn*13+kt
  int kt = w % 13;
  int pn = w / 13;
  int col = pn * 128 + cf * 16 + (lane & 15);
  int kb  = kt * 32 + ((lane >> 4) << 3);
  short8 o = (short8){0, 0, 0, 0, 0, 0, 0, 0};
  if (col < MPTS && kb < DIM) {   // DIM divisible by 8: chunks never straddle
    const float* p = sp + (size_t)col * DIM + kb;
    float4 a = *(const float4*)p;
    float4 b = *(const float4*)(p + 4);
    o[0] = (short)f2bf(a.x); o[1] = (short)f2bf(a.y);
    o[2] = (short)f2bf(a.z); o[3] = (short)f2bf(a.w);
    o[4] = (short)f2bf(b.x); o[5] = (short)f2bf(b.y);
    o[6] = (short)f2bf(b.z); o[7] = (short)f2bf(b.w);
  }
  Bsw[u] = o;
}

// ---------------------------------------------------------------------------
// Round-7 = round-6 + software-pipelined B reads from the LDS ring.
// R6 post-mortem: per-cstep 9940 cyc = MFMA 4035 + ds_read 4992 + overhead,
// SERIALIZED — inner loop's ds_read bf -> immediate MFMA(bf) chained the LDS
// and matrix pipes. Fix: register double-buffer bfc/bfn, issuing kt+1's 4
// ds_read_b128 BEFORE kt's 8 MFMAs; kt fully unrolled so copies rename away.
// Also hoist the wmv global loads to the cstep top (vmcnt hides under kt loop).
// Everything else (ring, prologue, epilogue) identical to R6.
// ---------------------------------------------------------------------------
__global__ __launch_bounds__(512, 1) void gemm_fused_kernel(
    const float* __restrict__ A,        // raw power_spectrum fp32 [N_ENV][DIM]
    const short8* __restrict__ Bsw,     // swizzled B fragments
    const float* __restrict__ wm,       // [MPAD]
    const int* __restrict__ row_seg,    // [N_ENV]
    float* __restrict__ out) {          // [NSTR]
  extern __shared__ unsigned char smem[];          // 2*RINGB = 106496 B
  unsigned short* As = (unsigned short*)smem;      // prologue staging view

  const int tid  = threadIdx.x;
  const int lane = tid & 63;
  const int wid  = tid >> 6;            // 0..7: owns rows [wid*32, wid*32+32)
  const int frow = lane & 15;
  const int koff = (lane >> 4) * 8;
  const long row_base = (long)blockIdx.x * BM;

  short8 af[2][13];                     // this wave's A, resident (VGPR/AGPR)

  // ---- Prologue: 4 chunks of 64 rows: stage -> normalize -> extract ------
  for (int ch = 0; ch < 4; ++ch) {
    const long rb = row_base + (long)ch * CHUNK;
    int rows_valid = (int)(N_ENV - rb);
    if (rows_valid > CHUNK) rows_valid = CHUNK;
    if (rows_valid < 0) rows_valid = 0;

    // stage: coalesced fp32 -> bf16 -> LDS (nontemporal: A has zero reuse)
    {
      const float4v* Ag = (const float4v*)(A + rb * DIM);
      for (int c = tid; c < CHUNK * (DIM / 4); c += 512) {  // 6400 chunks
        int row = c / 100;                                  // 100 float4/row
        int kc  = c - row * 100;
        uint2 packed = (uint2){0u, 0u};
        if (row < rows_valid) {
          float4v v = __builtin_nontemporal_load(&Ag[c]);
          packed.x = (unsigned int)f2bf(v[0]) | ((unsigned int)f2bf(v[1]) << 16);
          packed.y = (unsigned int)f2bf(v[2]) | ((unsigned int)f2bf(v[3]) << 16);
        }
        *(uint2*)&As[row * LDST + kc * 4] = packed;
      }
      if (tid < CHUNK) {   // zero K-pad [400,424): read by kt=12 fragments
        uint4 z = (uint4){0u, 0u, 0u, 0u};
        uint4* zp = (uint4*)&As[tid * LDST + 400];
        zp[0] = z; zp[1] = z; zp[2] = z;
      }
    }
    __syncthreads();

    // normalize in place: 8 threads per row, 52 shorts each
    {
      int row = tid >> 3, q = tid & 7;
      unsigned short* rp = &As[row * LDST + q * 52];
      short4v vals[13];
      float ss = 0.f;
#pragma unroll
      for (int i = 0; i < 13; ++i) {
        vals[i] = *(const short4v*)(rp + i * 4);
#pragma unroll
        for (int e = 0; e < 4; ++e) {
          float f = bf2f((unsigned short)vals[i][e]);
          ss += f * f;
        }
      }
      ss += __shfl_xor(ss, 1);
      ss += __shfl_xor(ss, 2);
      ss += __shfl_xor(ss, 4);
      float rn = (ss > 0.f) ? rsqrtf(ss) : 0.f;
#pragma unroll
      for (int i = 0; i < 13; ++i) {
        short4v o;
#pragma unroll
        for (int e = 0; e < 4; ++e)
          o[e] = (short)f2bf(bf2f((unsigned short)vals[i][e]) * rn);
        *(short4v*)(rp + i * 4) = o;
      }
    }
    __syncthreads();

    // extract: the two owning waves pull their 26 fragments into registers
    if ((wid >> 1) == ch) {
      const unsigned short* Ab = &As[((wid & 1) * 32 + frow) * LDST + koff];
#pragma unroll
      for (int i = 0; i < 2; ++i)
#pragma unroll
        for (int kt = 0; kt < 13; ++kt)
          af[i][kt] = *(const short8*)(Ab + i * (16 * LDST) + kt * 32);
    }
    __syncthreads();   // before next chunk (or ring) overwrites LDS
  }

  // ---- Main loop: LDS-ring B pipeline + register A -----------------------
  float vacc[2][4];
#pragma unroll
  for (int i = 0; i < 2; ++i)
#pragma unroll
    for (int r = 0; r < 4; ++r) vacc[i][r] = 0.f;

  // stage cstep s into ring buffer (s&1): 52 frags, spread over 8 waves
#define STAGE_CSTEP(s)                                                        \
  {                                                                           \
    const int pn_ = (s) >> 1, cfb_ = ((s) & 1) * 4;                           \
    unsigned char* buf_ = smem + (size_t)((s) & 1) * RINGB;                   \
    for (int f = wid; f < 52; f += 8) {                                       \
      int kt_ = f >> 2, j_ = f & 3;                                           \
      const short8* src_ =                                                    \
          Bsw + ((((size_t)pn_ * 13 + kt_) * 8) + cfb_ + j_) * 64 + lane;     \
      __builtin_amdgcn_global_load_lds(AS1(src_), AS3(buf_ + f * 1024),       \
                                       16, 0, 0);                             \
    }                                                                         \
  }

  STAGE_CSTEP(0);
  __syncthreads();   // compiler drains vmcnt before s_barrier -> buf0 ready

#pragma unroll 1
  for (int s = 0; s < CSTEPS; ++s) {
    if (s + 1 < CSTEPS) STAGE_CSTEP(s + 1);   // hidden under 13 kt of MFMA

    const unsigned short* buf =
        (const unsigned short*)(smem + (size_t)(s & 1) * RINGB);

    // wmv loads issued early: vmcnt drains under the kt loop
    float wmv[4];
#pragma unroll
    for (int j = 0; j < 4; ++j)
      wmv[j] = wm[s * 64 + j * 16 + frow];

    float4v acc[2][4];
#pragma unroll
    for (int i = 0; i < 2; ++i)
#pragma unroll
      for (int j = 0; j < 4; ++j) acc[i][j] = (float4v){0.f, 0.f, 0.f, 0.f};

    // software pipeline: ds_read for kt+1 issued before kt's MFMAs, so the
    // LDS pipe (4992 cyc/cstep) overlaps the matrix pipe (4035 cyc/cstep)
    short8 bfc[4], bfn[4];
#pragma unroll
    for (int j = 0; j < 4; ++j)
      bfc[j] = *(const short8*)(buf + j * 512 + lane * 8);

#pragma unroll
    for (int kt = 0; kt < KTILES; ++kt) {
      if (kt + 1 < KTILES) {
#pragma unroll
        for (int j = 0; j < 4; ++j)
          bfn[j] = *(const short8*)(buf + ((kt + 1) * 4 + j) * 512 + lane * 8);
      }
#pragma unroll
      for (int i = 0; i < 2; ++i)
#pragma unroll
        for (int j = 0; j < 4; ++j)
          acc[i][j] = __builtin_amdgcn_mfma_f32_16x16x32_bf16(
              af[i][kt], bfc[j], acc[i][j], 0, 0, 0);
      if (kt + 1 < KTILES) {
#pragma unroll
        for (int j = 0; j < 4; ++j) bfc[j] = bfn[j];
      }
    }

    // epilogue: vacc[row] += wm[col] * C^2 over this step's 4 col-frags
#pragma unroll
    for (int i = 0; i < 2; ++i)
#pragma unroll
      for (int r = 0; r < 4; ++r) {
        float sum = 0.f;
#pragma unroll
        for (int j = 0; j < 4; ++j) {
          float c = acc[i][j][r];
          sum += wmv[j] * c * c;
        }
        vacc[i][r] += sum;
      }

    __syncthreads();   // all waves done reading buf[s&1]; stage(s+1) drained
  }

  // cross-lane reduce over 16-lane groups (same C/D rows), then atomics
#pragma unroll
  for (int i = 0; i < 2; ++i)
#pragma unroll
    for (int r = 0; r < 4; ++r) {
      float s = vacc[i][r];
      s += __shfl_xor(s, 1);
      s += __shfl_xor(s, 2);
      s += __shfl_xor(s, 4);
      s += __shfl_xor(s, 8);
      if ((lane & 15) == 0) {
        long n = row_base + wid * 32 + i * 16 + (lane >> 4) * 4 + r;
        if (n < N_ENV) atomicAdd(&out[row_seg[n]], s);
      }
    }
}

// ---------------------------------------------------------------------------
extern "C" void kernel_launch(void* const* d_in, const int* in_sizes, int n_in,
                              void* d_out, int out_size, void* d_ws, size_t ws_size,
                              hipStream_t stream) {
  const float* ps      = (const float*)d_in[0];  // [N_ENV, DIM]
  const float* sp      = (const float*)d_in[1];  // [MPTS, DIM]
  const float* w       = (const float*)d_in[2];  // [1, NTRN]
  // d_in[3] = all_species: unused by the reference
  const int*   row_seg = (const int*)d_in[4];    // [N_ENV]
  const int*   col_seg = (const int*)d_in[5];    // [MPTS]
  float* out = (float*)d_out;                    // [NSTR]

  char* ws = (char*)d_ws;
  const size_t B_BYTES = (size_t)16 * KTILES * 8 * 64 * 16;  // 1,703,936
  short8* Bsw = (short8*)ws;
  float*  wm  = (float*)(ws + B_BYTES);

  const int LDS_BYTES = 2 * RINGB;   // 106496
  (void)hipFuncSetAttribute((const void*)gemm_fused_kernel,
                            hipFuncAttributeMaxDynamicSharedMemorySize,
                            LDS_BYTES);

  prep_kernel<<<MPAD / 256, 256, 0, stream>>>(w, col_seg, wm, out);
  bswz_kernel<<<(16 * KTILES * 8 * 64) / 256, 256, 0, stream>>>(sp, Bsw);
  gemm_fused_kernel<<<NBLK, 512, LDS_BYTES, stream>>>(ps, Bsw, wm, row_seg, out);
}